// Round 17
// baseline (327.519 us; speedup 1.0000x reference)
//
#include <hip/hip_runtime.h>

#define LN_EPS 1e-5f

typedef __attribute__((ext_vector_type(8))) short short8;
typedef __attribute__((ext_vector_type(4))) float f32x4;

// sigmoid via native exp + rcp (NO IEEE division)
__device__ __forceinline__ float sigf(float x) {
    return __builtin_amdgcn_rcpf(1.0f + __expf(-x));
}

__device__ __forceinline__ unsigned short f2bf(float f) {
    unsigned u = __float_as_uint(f);
    return (unsigned short)((u + 0x7fffu + ((u >> 16) & 1u)) >> 16);
}
__device__ __forceinline__ unsigned f2bf2(float lo, float hi) {
    return (unsigned)f2bf(lo) | ((unsigned)f2bf(hi) << 16);
}
__device__ __forceinline__ void bf2f(unsigned u, float& lo, float& hi) {
    lo = __uint_as_float(u << 16);
    hi = __uint_as_float(u & 0xffff0000u);
}
__device__ __forceinline__ void bf8f(uint4 p, float* o) {
    bf2f(p.x, o[0], o[1]); bf2f(p.y, o[2], o[3]);
    bf2f(p.z, o[4], o[5]); bf2f(p.w, o[6], o[7]);
}
__device__ __forceinline__ float bf1f(unsigned short s) {
    return __uint_as_float(((unsigned)s) << 16);
}

// butterfly sum over each quad via DPP quad_perm — no DS ops
__device__ __forceinline__ float quad_add_all(float x) {
    int v = __builtin_amdgcn_update_dpp(0, __float_as_int(x), 0xB1, 0xF, 0xF, true);
    x += __int_as_float(v);
    v = __builtin_amdgcn_update_dpp(0, __float_as_int(x), 0x4E, 0xF, 0xF, true);
    x += __int_as_float(v);
    return x;
}

// ---- weight prep: f32 [128][128] row-major -> fragment-linear bf16 ----
// plus packed (we,w2) bf16 pairs for att_edge
__global__ __launch_bounds__(256)
void prep_w(const float* __restrict__ lin_w, const float* __restrict__ msg_w1,
            const float* __restrict__ msg_w2, const float* __restrict__ att_w1,
            const float* __restrict__ out_w1, const float* __restrict__ out_w2,
            const float* __restrict__ att_b1, const float* __restrict__ att_w2,
            unsigned short* __restrict__ wp, float* __restrict__ bias256,
            unsigned* __restrict__ wpk)
{
    const int idx = blockIdx.x * 256 + threadIdx.x;
    if (idx < 8 * 16384) {
        const int m = idx >> 14, r = idx & 16383;
        const int k = r >> 7, n = r & 127;
        const float* src; int slot; int fnBase = 0;
        switch (m) {
            case 0: src = lin_w;  slot = 0; break;
            case 1: src = msg_w1; slot = 1; break;
            case 2: src = msg_w2; slot = 2; break;
            case 3: src = att_w1; slot = 3; break;
            case 4: src = att_w1 + 128 * 128; slot = 3; fnBase = 8; break;
            case 5: src = out_w1; slot = 5; break;
            default: src = out_w2; slot = 6; break;
        }
        const float v = src[k * 128 + n];
        const int fn = fnBase + (n >> 4);
        const int fk = k >> 5, kb = (k >> 3) & 3, j = k & 7;
        const size_t dst = (size_t)slot * 16384 + ((size_t)((fn * 4 + fk) * 64 + (n & 15) + 16 * kb)) * 8 + j;
        wp[dst] = f2bf(v);
    } else if (idx < 8 * 16384 + 256) {
        const int t = idx - 8 * 16384;
        bias256[t] = (t < 128) ? att_b1[t] : 0.f;
    } else if (idx < 8 * 16384 + 256 + 128) {
        const int t = idx - (8 * 16384 + 256);
        wpk[t] = (unsigned)f2bf(att_w1[256 * 128 + t]) | ((unsigned)f2bf(att_w2[t]) << 16);
    }
}

__device__ __forceinline__ short8 ldA_f32(const float* A, size_t row, int k0) {
    const float* ap = A + row * 128 + k0;
    const float4 f0 = *(const float4*)ap;
    const float4 f1 = *(const float4*)(ap + 4);
    union { unsigned u[4]; short8 s; } v;
    v.u[0] = f2bf2(f0.x, f0.y); v.u[1] = f2bf2(f0.z, f0.w);
    v.u[2] = f2bf2(f1.x, f1.y); v.u[3] = f2bf2(f1.z, f1.w);
    return v.s;
}
__device__ __forceinline__ short8 ldA_bf(const unsigned short* A, size_t row, int k0) {
    return *(const short8*)(A + row * 128 + k0);
}

// ---- fused FRONT kernel: block-staged B in LDS ----
__global__ __launch_bounds__(256, 3)
void front_mfma(const float* __restrict__ h,
                const unsigned short* __restrict__ wp, const float* __restrict__ lin_b,
                const float* __restrict__ att_b1,
                const float* __restrict__ msg_b1,
                const float* __restrict__ m1g, const float* __restrict__ m1b,
                const float* __restrict__ msg_b2,
                unsigned short* __restrict__ xbH, unsigned short* __restrict__ xrH,
                unsigned short* __restrict__ xcH, unsigned short* __restrict__ xmH,
                int nrows)
{
    __shared__ uint4 Bbuf[2048];                // 32 KiB: one 128x128 bf16 frag-linear W
    __shared__ unsigned short hof[4 * 2048];    // 16 KiB: 4 KiB per wave
    const int tid = threadIdx.x;
    const int w = tid >> 6, lane = tid & 63;
    const int r0 = blockIdx.x * 64;
    const int arow = r0 + w * 16 + (lane & 15);
    const size_t rowc = (arow < nrows) ? (size_t)arow : (size_t)(nrows - 1);
    const int kh = (lane >> 4) * 8;
    const int cn = lane & 15, rq = lane >> 4;
    unsigned short* hw = hof + w * 2048;
    const short8* Bf = (const short8*)Bbuf;

    short8 a[4];
#pragma unroll
    for (int fk = 0; fk < 4; ++fk) a[fk] = ldA_f32(h, rowc, fk * 32 + kh);

    const uint4* wp4 = (const uint4*)wp;

#define LOADB(slotoff)  { _Pragma("unroll") \
    for (int i = 0; i < 8; ++i) Bbuf[tid + i * 256] = wp4[(slotoff) + tid + i * 256]; }

#define MFMA8(afrag, accv) { _Pragma("unroll") \
    for (int fk = 0; fk < 4; ++fk) { _Pragma("unroll") \
        for (int fn = 0; fn < 8; ++fn) \
            accv[fn] = __builtin_amdgcn_mfma_f32_16x16x32_bf16(afrag[fk], Bf[(fn * 4 + fk) * 64 + lane], accv[fn], 0, 0, 0); } }

#define EPI_HOF(accv, bvv) { _Pragma("unroll") \
    for (int reg = 0; reg < 4; ++reg) { \
        const int row16 = rq * 4 + reg; const int sw = (row16 & 7) << 3; _Pragma("unroll") \
        for (int fn = 0; fn < 8; ++fn) \
            hw[row16 * 128 + ((fn * 16 + cn) ^ sw)] = f2bf(accv[fn][reg] + bvv[fn]); } }

#define FLUSH(G) { const int frow = lane >> 2; const int fgr = r0 + w * 16 + frow; \
    const int fsw = (frow & 7) << 3; _Pragma("unroll") \
    for (int it = 0; it < 4; ++it) { \
        const int c0 = ((lane & 3) + it * 4) * 8; \
        short8 v = *(const short8*)(hw + frow * 128 + (c0 ^ fsw)); \
        if (fgr < nrows) *(short8*)((G) + (size_t)fgr * 128 + c0) = v; } }

    // ---- stage 0: x = h @ lin_w + lin_b ----
    LOADB(0);
    __syncthreads();
    f32x4 acc[8];
#pragma unroll
    for (int fn = 0; fn < 8; ++fn) acc[fn] = (f32x4){0.f, 0.f, 0.f, 0.f};
    MFMA8(a, acc);
    {
        float bv[8];
#pragma unroll
        for (int fn = 0; fn < 8; ++fn) bv[fn] = lin_b[fn * 16 + cn];
        EPI_HOF(acc, bv);
    }
    short8 ax[4];
    {
        const int row16 = lane & 15;
        const int sw = (row16 & 7) << 3;
#pragma unroll
        for (int fk = 0; fk < 4; ++fk)
            ax[fk] = *(const short8*)(hw + row16 * 128 + ((fk * 32 + kh) ^ sw));
    }
    FLUSH(xbH);
    __syncthreads();

    // ---- stage 1: xr = x @ att_w1[:128] + att_b1 ----
    LOADB(3 * 2048);
    __syncthreads();
#pragma unroll
    for (int fn = 0; fn < 8; ++fn) acc[fn] = (f32x4){0.f, 0.f, 0.f, 0.f};
    MFMA8(ax, acc);
    {
        float bv[8];
#pragma unroll
        for (int fn = 0; fn < 8; ++fn) bv[fn] = att_b1[fn * 16 + cn];
        EPI_HOF(acc, bv);
    }
    FLUSH(xrH);
    __syncthreads();

    // ---- stage 2: xc = x @ att_w1[128:256] ----
    LOADB(4 * 2048);
    __syncthreads();
#pragma unroll
    for (int fn = 0; fn < 8; ++fn) acc[fn] = (f32x4){0.f, 0.f, 0.f, 0.f};
    MFMA8(ax, acc);
    {
        float bv[8];
#pragma unroll
        for (int fn = 0; fn < 8; ++fn) bv[fn] = 0.f;
        EPI_HOF(acc, bv);
    }
    FLUSH(xcH);
    __syncthreads();

    // ---- stage 3: m1 = LN(silu(x @ msg_w1 + msg_b1)) -> hof ----
    LOADB(1 * 2048);
    __syncthreads();
#pragma unroll
    for (int fn = 0; fn < 8; ++fn) acc[fn] = (f32x4){0.f, 0.f, 0.f, 0.f};
    MFMA8(ax, acc);
    {
        float bv[8], gv[8], bbv[8];
#pragma unroll
        for (int fn = 0; fn < 8; ++fn) {
            bv[fn] = msg_b1[fn * 16 + cn]; gv[fn] = m1g[fn * 16 + cn]; bbv[fn] = m1b[fn * 16 + cn];
        }
#pragma unroll
        for (int reg = 0; reg < 4; ++reg) {
            float val[8];
            float sum = 0.f, sq = 0.f;
#pragma unroll
            for (int fn = 0; fn < 8; ++fn) {
                float v = acc[fn][reg] + bv[fn];
                v = v * sigf(v);
                val[fn] = v; sum += v; sq += v * v;
            }
#pragma unroll
            for (int m = 1; m < 16; m <<= 1) { sum += __shfl_xor(sum, m); sq += __shfl_xor(sq, m); }
            const float mean = sum * (1.f / 128.f);
            const float var = sq * (1.f / 128.f) - mean * mean;
            const float rstd = rsqrtf(var + LN_EPS);
            const int row16 = rq * 4 + reg;
            const int sw = (row16 & 7) << 3;
#pragma unroll
            for (int fn = 0; fn < 8; ++fn) {
                const float o = (val[fn] - mean) * rstd * gv[fn] + bbv[fn];
                hw[row16 * 128 + ((fn * 16 + cn) ^ sw)] = f2bf(o);
            }
        }
    }
    short8 am[4];
    {
        const int row16 = lane & 15;
        const int sw = (row16 & 7) << 3;
#pragma unroll
        for (int fk = 0; fk < 4; ++fk)
            am[fk] = *(const short8*)(hw + row16 * 128 + ((fk * 32 + kh) ^ sw));
    }
    __syncthreads();

    // ---- stage 4: xm = m1 @ msg_w2 + msg_b2 ----
    LOADB(2 * 2048);
    __syncthreads();
#pragma unroll
    for (int fn = 0; fn < 8; ++fn) acc[fn] = (f32x4){0.f, 0.f, 0.f, 0.f};
    MFMA8(am, acc);
    {
        float bv[8];
#pragma unroll
        for (int fn = 0; fn < 8; ++fn) bv[fn] = msg_b2[fn * 16 + cn];
        EPI_HOF(acc, bv);
    }
    FLUSH(xmH);
#undef LOADB
#undef MFMA8
#undef EPI_HOF
#undef FLUSH
}

// ---- fused double GEMM (out-chain): C = LN(res + LN(silu(A@W1+b1))@W2 + b2) ----
__global__ __launch_bounds__(256, 4)
void gemm2_mfma(const unsigned short* __restrict__ Av,
                const unsigned short* __restrict__ Wp1, const float* __restrict__ b1,
                const float* __restrict__ ln1g, const float* __restrict__ ln1b,
                const unsigned short* __restrict__ Wp2, const float* __restrict__ b2,
                const float* __restrict__ ln2g, const float* __restrict__ ln2b,
                const unsigned short* __restrict__ resH, float* __restrict__ Cf, int nrows)
{
    __shared__ unsigned short hof[4 * 2048];
    const int tid = threadIdx.x;
    const int w = tid >> 6, lane = tid & 63;
    const int r0 = blockIdx.x * 64;
    const int arow = r0 + w * 16 + (lane & 15);
    const size_t rowc = (arow < nrows) ? (size_t)arow : (size_t)(nrows - 1);
    const int kh = (lane >> 4) * 8;
    const int cn = lane & 15, rq = lane >> 4;

    short8 a[4];
#pragma unroll
    for (int fk = 0; fk < 4; ++fk) a[fk] = ldA_bf(Av, rowc, fk * 32 + kh);

    const short8* B1f = (const short8*)Wp1;
    f32x4 acc[8];
#pragma unroll
    for (int fn = 0; fn < 8; ++fn) acc[fn] = (f32x4){0.f, 0.f, 0.f, 0.f};
#pragma unroll
    for (int fk = 0; fk < 4; ++fk)
#pragma unroll
        for (int fn = 0; fn < 8; ++fn)
            acc[fn] = __builtin_amdgcn_mfma_f32_16x16x32_bf16(a[fk], B1f[(fn * 4 + fk) * 64 + lane], acc[fn], 0, 0, 0);

    unsigned short* hw = hof + w * 2048;
    {
        float bv[8], gv[8], bbv[8];
#pragma unroll
        for (int fn = 0; fn < 8; ++fn) {
            bv[fn] = b1[fn * 16 + cn]; gv[fn] = ln1g[fn * 16 + cn]; bbv[fn] = ln1b[fn * 16 + cn];
        }
#pragma unroll
        for (int reg = 0; reg < 4; ++reg) {
            float val[8];
            float sum = 0.f, sq = 0.f;
#pragma unroll
            for (int fn = 0; fn < 8; ++fn) {
                float v = acc[fn][reg] + bv[fn];
                v = v * sigf(v);
                val[fn] = v; sum += v; sq += v * v;
            }
#pragma unroll
            for (int m = 1; m < 16; m <<= 1) { sum += __shfl_xor(sum, m); sq += __shfl_xor(sq, m); }
            const float mean = sum * (1.f / 128.f);
            const float var = sq * (1.f / 128.f) - mean * mean;
            const float rstd = rsqrtf(var + LN_EPS);
            const int row16 = rq * 4 + reg;
            const int sw = (row16 & 7) << 3;
#pragma unroll
            for (int fn = 0; fn < 8; ++fn) {
                const float o = (val[fn] - mean) * rstd * gv[fn] + bbv[fn];
                hw[row16 * 128 + ((fn * 16 + cn) ^ sw)] = f2bf(o);
            }
        }
    }

    short8 a2[4];
    {
        const int row16 = lane & 15;
        const int sw = (row16 & 7) << 3;
#pragma unroll
        for (int fk = 0; fk < 4; ++fk)
            a2[fk] = *(const short8*)(hw + row16 * 128 + ((fk * 32 + kh) ^ sw));
    }

    const short8* B2f = (const short8*)Wp2;
    f32x4 acc2[8];
#pragma unroll
    for (int fn = 0; fn < 8; ++fn) acc2[fn] = (f32x4){0.f, 0.f, 0.f, 0.f};
#pragma unroll
    for (int fk = 0; fk < 4; ++fk)
#pragma unroll
        for (int fn = 0; fn < 8; ++fn)
            acc2[fn] = __builtin_amdgcn_mfma_f32_16x16x32_bf16(a2[fk], B2f[(fn * 4 + fk) * 64 + lane], acc2[fn], 0, 0, 0);

    float bv2[8], gv[8], bbv[8];
#pragma unroll
    for (int fn = 0; fn < 8; ++fn) {
        bv2[fn] = b2[fn * 16 + cn]; gv[fn] = ln2g[fn * 16 + cn]; bbv[fn] = ln2b[fn * 16 + cn];
    }
#pragma unroll
    for (int reg = 0; reg < 4; ++reg) {
        const int gr = r0 + w * 16 + rq * 4 + reg;
        const int grc = gr < nrows ? gr : nrows - 1;
        float val[8];
        float sum = 0.f, sq = 0.f;
#pragma unroll
        for (int fn = 0; fn < 8; ++fn) {
            float v = acc2[fn][reg] + bv2[fn] + bf1f(resH[(size_t)grc * 128 + fn * 16 + cn]);
            val[fn] = v; sum += v; sq += v * v;
        }
#pragma unroll
        for (int m = 1; m < 16; m <<= 1) { sum += __shfl_xor(sum, m); sq += __shfl_xor(sq, m); }
        const float mean = sum * (1.f / 128.f);
        const float var = sq * (1.f / 128.f) - mean * mean;
        const float rstd = rsqrtf(var + LN_EPS);
        if (gr < nrows) {
#pragma unroll
            for (int fn = 0; fn < 8; ++fn)
                Cf[(size_t)gr * 128 + fn * 16 + cn] = (val[fn] - mean) * rstd * gv[fn] + bbv[fn];
        }
    }
}

// ---- histogram + per-edge rank in ONE atomic pass (8-deep ILP) ----
__global__ __launch_bounds__(256, 8)
void hist_rank(const int* __restrict__ row, int* __restrict__ cnt,
               int* __restrict__ rank, int E)
{
    const int tid = blockIdx.x * blockDim.x + threadIdx.x;
    const int stride = gridDim.x * blockDim.x;
    for (int e0 = tid; e0 < E; e0 += stride * 8) {
        int r[8]; bool val[8];
#pragma unroll
        for (int u = 0; u < 8; ++u) {
            const int e = e0 + u * stride;
            val[u] = e < E;
            r[u] = val[u] ? row[e] : 0;
        }
        int rk[8];
#pragma unroll
        for (int u = 0; u < 8; ++u)
            if (val[u]) rk[u] = atomicAdd(&cnt[r[u]], 1);
#pragma unroll
        for (int u = 0; u < 8; ++u)
            if (val[u]) rank[e0 + u * stride] = rk[u];
    }
}

__global__ __launch_bounds__(1024)
void scan_a(const int* __restrict__ cnt, int* __restrict__ off,
            int* __restrict__ btot, int n)
{
    __shared__ int wsum[16];
    const int tid = threadIdx.x, lane = tid & 63, wv = tid >> 6;
    const int i = blockIdx.x * 1024 + tid;
    const int v = (i < n) ? cnt[i] : 0;
    int incl = v;
#pragma unroll
    for (int d = 1; d < 64; d <<= 1) { int t = __shfl_up(incl, d); if (lane >= d) incl += t; }
    if (lane == 63) wsum[wv] = incl;
    __syncthreads();
    if (tid == 0) {
        int run = 0;
        for (int ww = 0; ww < 16; ++ww) { int t = wsum[ww]; wsum[ww] = run; run += t; }
    }
    __syncthreads();
    if (i < n) off[i] = wsum[wv] + incl - v;
    if (tid == 1023) btot[blockIdx.x] = wsum[15] + incl;
}

__global__ __launch_bounds__(64)
void scan_b(int* __restrict__ btot, int* __restrict__ bexc,
            int* __restrict__ off, int n, int nb, int E)
{
    const int t = threadIdx.x;
    const int v = (t < nb) ? btot[t] : 0;
    int incl = v;
#pragma unroll
    for (int d = 1; d < 64; d <<= 1) { int u = __shfl_up(incl, d); if (t >= d) incl += u; }
    if (t < nb) bexc[t] = incl - v;
    if (t == 0) off[n] = E;
}

__global__ __launch_bounds__(1024)
void scan_c(int* __restrict__ off, const int* __restrict__ bexc, int n)
{
    const int i = blockIdx.x * 1024 + threadIdx.x;
    if (i < n) off[i] += bexc[blockIdx.x];
}

// ---- edge-parallel attention: ONE edge/quad, packed weights, META PIPELINE ----
// launch_bounds (256,8): kernel fits 64 VGPR exactly -> target full 8 waves/EU
__global__ __launch_bounds__(256, 8)
void att_edge(const unsigned short* __restrict__ xrH,
              const unsigned short* __restrict__ xcH,
              const int* __restrict__ row, const int* __restrict__ col,
              const float* __restrict__ ea, const float* __restrict__ em,
              const int* __restrict__ rank, const int* __restrict__ off,
              const unsigned* __restrict__ wpk, const float* __restrict__ b2p,
              uint2* __restrict__ catS, int E)
{
    const int lane = threadIdx.x & 63;
    const int q = lane & 3;
    const int gwid = (blockIdx.x * blockDim.x + threadIdx.x) >> 6;
    const int nw = (gridDim.x * blockDim.x) >> 6;

    unsigned wk[32];
#pragma unroll
    for (int ch = 0; ch < 4; ++ch) {
        const uint4 k0 = ((const uint4*)wpk)[ch * 8 + q * 2];
        const uint4 k1 = ((const uint4*)wpk)[ch * 8 + q * 2 + 1];
        wk[ch * 8 + 0] = k0.x; wk[ch * 8 + 1] = k0.y; wk[ch * 8 + 2] = k0.z; wk[ch * 8 + 3] = k0.w;
        wk[ch * 8 + 4] = k1.x; wk[ch * 8 + 5] = k1.y; wk[ch * 8 + 6] = k1.z; wk[ch * 8 + 7] = k1.w;
    }
    const float b2 = *b2p;

    int base = gwid * 16;
    if (base >= E) return;

    int e = base + (lane >> 2);
    bool valid = e < E;
    int ec = valid ? e : E - 1;
    int r = row[ec], c = col[ec];
    float eax = ea[ec], emv = em[ec];
    int rk = rank[ec], ofr = off[r];

    while (true) {
        const unsigned short* xr = xrH + (size_t)r * 128 + q * 8;
        const unsigned short* xc = xcH + (size_t)c * 128 + q * 8;
        uint4 pa[4], pb[4];
#pragma unroll
        for (int ch = 0; ch < 4; ++ch) {
            pa[ch] = *(const uint4*)(xr + ch * 32);
            pb[ch] = *(const uint4*)(xc + ch * 32);
        }

        const int nbase = base + nw * 16;
        const bool more = nbase < E;
        int r2 = 0, c2 = 0, rk2 = 0, ofr2 = 0;
        float eax2 = 0.f, emv2 = 0.f;
        bool valid2 = false;
        if (more) {
            const int e2 = nbase + (lane >> 2);
            valid2 = e2 < E;
            const int ec2 = valid2 ? e2 : E - 1;
            r2 = row[ec2]; c2 = col[ec2];
            eax2 = ea[ec2]; emv2 = em[ec2];
            rk2 = rank[ec2]; ofr2 = off[r2];
        }

        float pc[4];
#pragma unroll
        for (int ch = 0; ch < 4; ++ch) {
            float xa[8], xb[8];
            bf8f(pa[ch], xa); bf8f(pb[ch], xb);
            float s = 0.f;
#pragma unroll
            for (int i = 0; i < 8; ++i) {
                const unsigned wv = wk[ch * 8 + i];
                const float weF = __uint_as_float(wv << 16);
                const float w2F = __uint_as_float(wv & 0xffff0000u);
                const float t = xa[i] + xb[i] + eax * weF;
                s += t * sigf(t) * w2F;
            }
            pc[ch] = s;
        }
        float p = (pc[0] + pc[1]) + (pc[2] + pc[3]);
        p = quad_add_all(p);
        const float att = sigf(p + b2) * emv;
        if (valid && q == 0)
            catS[ofr + rk] = make_uint2((unsigned)c, __float_as_uint(att));

        if (!more) break;
        base = nbase;
        valid = valid2; r = r2; c = c2; eax = eax2; emv = emv2; rk = rk2; ofr = ofr2;
    }
}

// ---- row accumulation: msgH[r] = bf16( sum att * xm[col] ) ----
__global__ __launch_bounds__(256, 8)
void accum_k(const unsigned short* __restrict__ xmH, const int* __restrict__ off,
             const uint2* __restrict__ catS, unsigned short* __restrict__ msgH, int N)
{
    const int lane = threadIdx.x & 63;
    const int g = lane >> 4, l = lane & 15;
    const int gwid = (blockIdx.x * blockDim.x + threadIdx.x) >> 6;
    const int nw = (gridDim.x * blockDim.x) >> 6;
    const uint4* xm4 = (const uint4*)xmH;

    for (int wid = gwid; wid < N; wid += nw) {
        int j0 = off[wid];
        const int jend = off[wid + 1];
        float acc[8] = {0.f, 0.f, 0.f, 0.f, 0.f, 0.f, 0.f, 0.f};

        for (; j0 + 16 <= jend; j0 += 16) {
            uint2 ca[4]; uint4 pk[4];
#pragma unroll
            for (int u = 0; u < 4; ++u) ca[u] = catS[j0 + u * 4 + g];
#pragma unroll
            for (int u = 0; u < 4; ++u) pk[u] = xm4[(size_t)ca[u].x * 16 + l];
#pragma unroll
            for (int u = 0; u < 4; ++u) {
                const float att = __uint_as_float(ca[u].y);
                float xm[8];
                bf8f(pk[u], xm);
#pragma unroll
                for (int i = 0; i < 8; ++i) acc[i] = fmaf(att, xm[i], acc[i]);
            }
        }
        for (; j0 + 8 <= jend; j0 += 8) {
            const uint2 caA = catS[j0 + g];
            const uint2 caB = catS[j0 + 4 + g];
            const uint4 pA = xm4[(size_t)caA.x * 16 + l];
            const uint4 pB = xm4[(size_t)caB.x * 16 + l];
            const float attA = __uint_as_float(caA.y);
            const float attB = __uint_as_float(caB.y);
            float xmA[8], xmB[8];
            bf8f(pA, xmA); bf8f(pB, xmB);
#pragma unroll
            for (int i = 0; i < 8; ++i)
                acc[i] = fmaf(attB, xmB[i], fmaf(attA, xmA[i], acc[i]));
        }
        for (; j0 < jend; j0 += 4) {
            const int je = j0 + g;
            const bool valid = je < jend;
            const int jc = valid ? je : jend - 1;
            const uint2 ca = catS[jc];
            const uint4 p = xm4[(size_t)ca.x * 16 + l];
            const float att = valid ? __uint_as_float(ca.y) : 0.f;
            float xm[8];
            bf8f(p, xm);
#pragma unroll
            for (int i = 0; i < 8; ++i) acc[i] = fmaf(att, xm[i], acc[i]);
        }

#pragma unroll
        for (int i = 0; i < 8; ++i) {
            acc[i] += __shfl_xor(acc[i], 16);
            acc[i] += __shfl_xor(acc[i], 32);
        }
        if (g == 0) {
            uint4 pk;
            pk.x = f2bf2(acc[0], acc[1]); pk.y = f2bf2(acc[2], acc[3]);
            pk.z = f2bf2(acc[4], acc[5]); pk.w = f2bf2(acc[6], acc[7]);
            ((uint4*)msgH)[(size_t)wid * 16 + l] = pk;
        }
    }
}

extern "C" void kernel_launch(void* const* d_in, const int* in_sizes, int n_in,
                              void* d_out, int out_size, void* d_ws, size_t ws_size,
                              hipStream_t stream)
{
    const float* h        = (const float*)d_in[0];
    const float* edge_attr= (const float*)d_in[1];
    const int*   row      = (const int*)d_in[2];
    const int*   col      = (const int*)d_in[3];
    const float* edge_mask= (const float*)d_in[5];
    const float* lin_w    = (const float*)d_in[6];
    const float* lin_b    = (const float*)d_in[7];
    const float* msg_w1   = (const float*)d_in[8];
    const float* msg_b1   = (const float*)d_in[9];
    const float* msg_ln_g = (const float*)d_in[10];
    const float* msg_ln_b = (const float*)d_in[11];
    const float* msg_w2   = (const float*)d_in[12];
    const float* msg_b2   = (const float*)d_in[13];
    const float* att_w1   = (const float*)d_in[14];
    const float* att_b1   = (const float*)d_in[15];
    const float* att_w2   = (const float*)d_in[16];
    const float* att_b2   = (const float*)d_in[17];
    const float* out_w1   = (const float*)d_in[18];
    const float* out_b1   = (const float*)d_in[19];
    const float* out_ln_g = (const float*)d_in[20];
    const float* out_ln_b = (const float*)d_in[21];
    const float* out_w2   = (const float*)d_in[22];
    const float* out_b2   = (const float*)d_in[23];
    const float* ln_g     = (const float*)d_in[24];
    const float* ln_b     = (const float*)d_in[25];

    const int N = in_sizes[0] / 128;
    const int E = in_sizes[2];
    const size_t NF = (size_t)N * 128;

    unsigned short* xbH  = (unsigned short*)d_ws;       // bf16 [N][128] x
    unsigned short* xrH  = xbH + NF;                    // bf16 [N][128]
    unsigned short* xcH  = xrH + NF;                    // bf16 [N][128]
    unsigned short* xmH  = xcH + NF;                    // bf16 [N][128]
    unsigned short* msgH = xmH + NF;                    // bf16 [N][128]
    int*    cnt   = (int*)(msgH + NF);                  // N
    int*    off   = cnt + N;                            // N+1 (alloc N+8)
    int*    btot  = off + N + 8;                        // 64
    int*    bexc  = btot + 64;                          // 64
    int*    rank  = bexc + 64;                          // E
    uint2*  catS  = (uint2*)(rank + E);                 // E
    unsigned short* wp = (unsigned short*)(catS + E);   // 8*16384 bf16
    float* bias256 = (float*)(wp + 8 * 16384);          // 256 f32
    unsigned* wpk  = (unsigned*)(bias256 + 256);        // 128 u32 packed (we,w2)

    const int gb = (N + 63) / 64;
    const int nb = (N + 1023) / 1024;
    const int hgrid = (E + 256 * 8 - 1) / (256 * 8);

    prep_w<<<514, 256, 0, stream>>>(lin_w, msg_w1, msg_w2, att_w1, out_w1, out_w2,
                                    att_b1, att_w2, wp, bias256, wpk);
    hipMemsetAsync(cnt, 0, (size_t)N * sizeof(int), stream);
    hist_rank<<<hgrid, 256, 0, stream>>>(row, cnt, rank, E);
    scan_a<<<nb, 1024, 0, stream>>>(cnt, off, btot, N);
    scan_b<<<1, 64, 0, stream>>>(btot, bexc, off, N, nb, E);
    scan_c<<<nb, 1024, 0, stream>>>(off, bexc, N);

    // fused front: lin -> {att_r, att_c, msg1 -> msg2}, LDS-staged B
    front_mfma<<<gb, 256, 0, stream>>>(h, wp, lin_b, att_b1,
                                       msg_b1, msg_ln_g, msg_ln_b, msg_b2,
                                       xbH, xrH, xcH, xmH, N);

    // att scalars: 1 edge/quad, packed weights, meta-pipelined, fused scatter
    att_edge<<<2048, 256, 0, stream>>>(xrH, xcH, row, col, edge_attr, edge_mask,
                                       rank, off, wpk, att_b2, catS, E);

    // msg[r] = sum att * xm[col]  (bf16 out)
    accum_k<<<2048, 256, 0, stream>>>(xmH, off, catS, msgH, N);

    // out = LN(x + (LN(silu(msg @ out_w1 + out_b1))) @ out_w2 + out_b2)
    gemm2_mfma<<<gb, 256, 0, stream>>>(msgH, wp + 5 * 16384, out_b1, out_ln_g, out_ln_b,
                                       wp + 6 * 16384, out_b2, ln_g, ln_b,
                                       xbH, (float*)d_out, N);
}

// Round 18
// 202.052 us; speedup vs baseline: 1.6210x; 1.6210x over previous
//
#include <hip/hip_runtime.h>

#define LN_EPS 1e-5f

typedef __attribute__((ext_vector_type(8))) short short8;
typedef __attribute__((ext_vector_type(4))) float f32x4;

// sigmoid via native exp + rcp (NO IEEE division)
__device__ __forceinline__ float sigf(float x) {
    return __builtin_amdgcn_rcpf(1.0f + __expf(-x));
}

__device__ __forceinline__ unsigned short f2bf(float f) {
    unsigned u = __float_as_uint(f);
    return (unsigned short)((u + 0x7fffu + ((u >> 16) & 1u)) >> 16);
}
__device__ __forceinline__ unsigned f2bf2(float lo, float hi) {
    return (unsigned)f2bf(lo) | ((unsigned)f2bf(hi) << 16);
}
__device__ __forceinline__ void bf2f(unsigned u, float& lo, float& hi) {
    lo = __uint_as_float(u << 16);
    hi = __uint_as_float(u & 0xffff0000u);
}
__device__ __forceinline__ void bf8f(uint4 p, float* o) {
    bf2f(p.x, o[0], o[1]); bf2f(p.y, o[2], o[3]);
    bf2f(p.z, o[4], o[5]); bf2f(p.w, o[6], o[7]);
}
__device__ __forceinline__ float bf1f(unsigned short s) {
    return __uint_as_float(((unsigned)s) << 16);
}

// butterfly sum over each quad via DPP quad_perm — no DS ops
__device__ __forceinline__ float quad_add_all(float x) {
    int v = __builtin_amdgcn_update_dpp(0, __float_as_int(x), 0xB1, 0xF, 0xF, true);
    x += __int_as_float(v);
    v = __builtin_amdgcn_update_dpp(0, __float_as_int(x), 0x4E, 0xF, 0xF, true);
    x += __int_as_float(v);
    return x;
}

// ---- weight prep: f32 [128][128] row-major -> fragment-linear bf16 ----
// plus packed (we,w2) bf16 pairs for att_edge
__global__ __launch_bounds__(256)
void prep_w(const float* __restrict__ lin_w, const float* __restrict__ msg_w1,
            const float* __restrict__ msg_w2, const float* __restrict__ att_w1,
            const float* __restrict__ out_w1, const float* __restrict__ out_w2,
            const float* __restrict__ att_b1, const float* __restrict__ att_w2,
            unsigned short* __restrict__ wp, float* __restrict__ bias256,
            unsigned* __restrict__ wpk)
{
    const int idx = blockIdx.x * 256 + threadIdx.x;
    if (idx < 8 * 16384) {
        const int m = idx >> 14, r = idx & 16383;
        const int k = r >> 7, n = r & 127;
        const float* src; int slot; int fnBase = 0;
        switch (m) {
            case 0: src = lin_w;  slot = 0; break;
            case 1: src = msg_w1; slot = 1; break;
            case 2: src = msg_w2; slot = 2; break;
            case 3: src = att_w1; slot = 3; break;
            case 4: src = att_w1 + 128 * 128; slot = 3; fnBase = 8; break;
            case 5: src = out_w1; slot = 5; break;
            default: src = out_w2; slot = 6; break;
        }
        const float v = src[k * 128 + n];
        const int fn = fnBase + (n >> 4);
        const int fk = k >> 5, kb = (k >> 3) & 3, j = k & 7;
        const size_t dst = (size_t)slot * 16384 + ((size_t)((fn * 4 + fk) * 64 + (n & 15) + 16 * kb)) * 8 + j;
        wp[dst] = f2bf(v);
    } else if (idx < 8 * 16384 + 256) {
        const int t = idx - 8 * 16384;
        bias256[t] = (t < 128) ? att_b1[t] : 0.f;
    } else if (idx < 8 * 16384 + 256 + 128) {
        const int t = idx - (8 * 16384 + 256);
        wpk[t] = (unsigned)f2bf(att_w1[256 * 128 + t]) | ((unsigned)f2bf(att_w2[t]) << 16);
    }
}

__device__ __forceinline__ short8 ldA_f32(const float* A, size_t row, int k0) {
    const float* ap = A + row * 128 + k0;
    const float4 f0 = *(const float4*)ap;
    const float4 f1 = *(const float4*)(ap + 4);
    union { unsigned u[4]; short8 s; } v;
    v.u[0] = f2bf2(f0.x, f0.y); v.u[1] = f2bf2(f0.z, f0.w);
    v.u[2] = f2bf2(f1.x, f1.y); v.u[3] = f2bf2(f1.z, f1.w);
    return v.s;
}
__device__ __forceinline__ short8 ldA_bf(const unsigned short* A, size_t row, int k0) {
    return *(const short8*)(A + row * 128 + k0);
}

// ---- fused FRONT kernel: block-staged B in LDS ----
__global__ __launch_bounds__(256, 3)
void front_mfma(const float* __restrict__ h,
                const unsigned short* __restrict__ wp, const float* __restrict__ lin_b,
                const float* __restrict__ att_b1,
                const float* __restrict__ msg_b1,
                const float* __restrict__ m1g, const float* __restrict__ m1b,
                const float* __restrict__ msg_b2,
                unsigned short* __restrict__ xbH, unsigned short* __restrict__ xrH,
                unsigned short* __restrict__ xcH, unsigned short* __restrict__ xmH,
                int nrows)
{
    __shared__ uint4 Bbuf[2048];                // 32 KiB: one 128x128 bf16 frag-linear W
    __shared__ unsigned short hof[4 * 2048];    // 16 KiB: 4 KiB per wave
    const int tid = threadIdx.x;
    const int w = tid >> 6, lane = tid & 63;
    const int r0 = blockIdx.x * 64;
    const int arow = r0 + w * 16 + (lane & 15);
    const size_t rowc = (arow < nrows) ? (size_t)arow : (size_t)(nrows - 1);
    const int kh = (lane >> 4) * 8;
    const int cn = lane & 15, rq = lane >> 4;
    unsigned short* hw = hof + w * 2048;
    const short8* Bf = (const short8*)Bbuf;

    short8 a[4];
#pragma unroll
    for (int fk = 0; fk < 4; ++fk) a[fk] = ldA_f32(h, rowc, fk * 32 + kh);

    const uint4* wp4 = (const uint4*)wp;

#define LOADB(slotoff)  { _Pragma("unroll") \
    for (int i = 0; i < 8; ++i) Bbuf[tid + i * 256] = wp4[(slotoff) + tid + i * 256]; }

#define MFMA8(afrag, accv) { _Pragma("unroll") \
    for (int fk = 0; fk < 4; ++fk) { _Pragma("unroll") \
        for (int fn = 0; fn < 8; ++fn) \
            accv[fn] = __builtin_amdgcn_mfma_f32_16x16x32_bf16(afrag[fk], Bf[(fn * 4 + fk) * 64 + lane], accv[fn], 0, 0, 0); } }

#define EPI_HOF(accv, bvv) { _Pragma("unroll") \
    for (int reg = 0; reg < 4; ++reg) { \
        const int row16 = rq * 4 + reg; const int sw = (row16 & 7) << 3; _Pragma("unroll") \
        for (int fn = 0; fn < 8; ++fn) \
            hw[row16 * 128 + ((fn * 16 + cn) ^ sw)] = f2bf(accv[fn][reg] + bvv[fn]); } }

#define FLUSH(G) { const int frow = lane >> 2; const int fgr = r0 + w * 16 + frow; \
    const int fsw = (frow & 7) << 3; _Pragma("unroll") \
    for (int it = 0; it < 4; ++it) { \
        const int c0 = ((lane & 3) + it * 4) * 8; \
        short8 v = *(const short8*)(hw + frow * 128 + (c0 ^ fsw)); \
        if (fgr < nrows) *(short8*)((G) + (size_t)fgr * 128 + c0) = v; } }

    // ---- stage 0: x = h @ lin_w + lin_b ----
    LOADB(0);
    __syncthreads();
    f32x4 acc[8];
#pragma unroll
    for (int fn = 0; fn < 8; ++fn) acc[fn] = (f32x4){0.f, 0.f, 0.f, 0.f};
    MFMA8(a, acc);
    {
        float bv[8];
#pragma unroll
        for (int fn = 0; fn < 8; ++fn) bv[fn] = lin_b[fn * 16 + cn];
        EPI_HOF(acc, bv);
    }
    short8 ax[4];
    {
        const int row16 = lane & 15;
        const int sw = (row16 & 7) << 3;
#pragma unroll
        for (int fk = 0; fk < 4; ++fk)
            ax[fk] = *(const short8*)(hw + row16 * 128 + ((fk * 32 + kh) ^ sw));
    }
    FLUSH(xbH);
    __syncthreads();

    // ---- stage 1: xr = x @ att_w1[:128] + att_b1 ----
    LOADB(3 * 2048);
    __syncthreads();
#pragma unroll
    for (int fn = 0; fn < 8; ++fn) acc[fn] = (f32x4){0.f, 0.f, 0.f, 0.f};
    MFMA8(ax, acc);
    {
        float bv[8];
#pragma unroll
        for (int fn = 0; fn < 8; ++fn) bv[fn] = att_b1[fn * 16 + cn];
        EPI_HOF(acc, bv);
    }
    FLUSH(xrH);
    __syncthreads();

    // ---- stage 2: xc = x @ att_w1[128:256] ----
    LOADB(4 * 2048);
    __syncthreads();
#pragma unroll
    for (int fn = 0; fn < 8; ++fn) acc[fn] = (f32x4){0.f, 0.f, 0.f, 0.f};
    MFMA8(ax, acc);
    {
        float bv[8];
#pragma unroll
        for (int fn = 0; fn < 8; ++fn) bv[fn] = 0.f;
        EPI_HOF(acc, bv);
    }
    FLUSH(xcH);
    __syncthreads();

    // ---- stage 3: m1 = LN(silu(x @ msg_w1 + msg_b1)) -> hof ----
    LOADB(1 * 2048);
    __syncthreads();
#pragma unroll
    for (int fn = 0; fn < 8; ++fn) acc[fn] = (f32x4){0.f, 0.f, 0.f, 0.f};
    MFMA8(ax, acc);
    {
        float bv[8], gv[8], bbv[8];
#pragma unroll
        for (int fn = 0; fn < 8; ++fn) {
            bv[fn] = msg_b1[fn * 16 + cn]; gv[fn] = m1g[fn * 16 + cn]; bbv[fn] = m1b[fn * 16 + cn];
        }
#pragma unroll
        for (int reg = 0; reg < 4; ++reg) {
            float val[8];
            float sum = 0.f, sq = 0.f;
#pragma unroll
            for (int fn = 0; fn < 8; ++fn) {
                float v = acc[fn][reg] + bv[fn];
                v = v * sigf(v);
                val[fn] = v; sum += v; sq += v * v;
            }
#pragma unroll
            for (int m = 1; m < 16; m <<= 1) { sum += __shfl_xor(sum, m); sq += __shfl_xor(sq, m); }
            const float mean = sum * (1.f / 128.f);
            const float var = sq * (1.f / 128.f) - mean * mean;
            const float rstd = rsqrtf(var + LN_EPS);
            const int row16 = rq * 4 + reg;
            const int sw = (row16 & 7) << 3;
#pragma unroll
            for (int fn = 0; fn < 8; ++fn) {
                const float o = (val[fn] - mean) * rstd * gv[fn] + bbv[fn];
                hw[row16 * 128 + ((fn * 16 + cn) ^ sw)] = f2bf(o);
            }
        }
    }
    short8 am[4];
    {
        const int row16 = lane & 15;
        const int sw = (row16 & 7) << 3;
#pragma unroll
        for (int fk = 0; fk < 4; ++fk)
            am[fk] = *(const short8*)(hw + row16 * 128 + ((fk * 32 + kh) ^ sw));
    }
    __syncthreads();

    // ---- stage 4: xm = m1 @ msg_w2 + msg_b2 ----
    LOADB(2 * 2048);
    __syncthreads();
#pragma unroll
    for (int fn = 0; fn < 8; ++fn) acc[fn] = (f32x4){0.f, 0.f, 0.f, 0.f};
    MFMA8(am, acc);
    {
        float bv[8];
#pragma unroll
        for (int fn = 0; fn < 8; ++fn) bv[fn] = msg_b2[fn * 16 + cn];
        EPI_HOF(acc, bv);
    }
    FLUSH(xmH);
#undef LOADB
#undef MFMA8
#undef EPI_HOF
#undef FLUSH
}

// ---- fused double GEMM (out-chain): C = LN(res + LN(silu(A@W1+b1))@W2 + b2) ----
__global__ __launch_bounds__(256, 4)
void gemm2_mfma(const unsigned short* __restrict__ Av,
                const unsigned short* __restrict__ Wp1, const float* __restrict__ b1,
                const float* __restrict__ ln1g, const float* __restrict__ ln1b,
                const unsigned short* __restrict__ Wp2, const float* __restrict__ b2,
                const float* __restrict__ ln2g, const float* __restrict__ ln2b,
                const unsigned short* __restrict__ resH, float* __restrict__ Cf, int nrows)
{
    __shared__ unsigned short hof[4 * 2048];
    const int tid = threadIdx.x;
    const int w = tid >> 6, lane = tid & 63;
    const int r0 = blockIdx.x * 64;
    const int arow = r0 + w * 16 + (lane & 15);
    const size_t rowc = (arow < nrows) ? (size_t)arow : (size_t)(nrows - 1);
    const int kh = (lane >> 4) * 8;
    const int cn = lane & 15, rq = lane >> 4;

    short8 a[4];
#pragma unroll
    for (int fk = 0; fk < 4; ++fk) a[fk] = ldA_bf(Av, rowc, fk * 32 + kh);

    const short8* B1f = (const short8*)Wp1;
    f32x4 acc[8];
#pragma unroll
    for (int fn = 0; fn < 8; ++fn) acc[fn] = (f32x4){0.f, 0.f, 0.f, 0.f};
#pragma unroll
    for (int fk = 0; fk < 4; ++fk)
#pragma unroll
        for (int fn = 0; fn < 8; ++fn)
            acc[fn] = __builtin_amdgcn_mfma_f32_16x16x32_bf16(a[fk], B1f[(fn * 4 + fk) * 64 + lane], acc[fn], 0, 0, 0);

    unsigned short* hw = hof + w * 2048;
    {
        float bv[8], gv[8], bbv[8];
#pragma unroll
        for (int fn = 0; fn < 8; ++fn) {
            bv[fn] = b1[fn * 16 + cn]; gv[fn] = ln1g[fn * 16 + cn]; bbv[fn] = ln1b[fn * 16 + cn];
        }
#pragma unroll
        for (int reg = 0; reg < 4; ++reg) {
            float val[8];
            float sum = 0.f, sq = 0.f;
#pragma unroll
            for (int fn = 0; fn < 8; ++fn) {
                float v = acc[fn][reg] + bv[fn];
                v = v * sigf(v);
                val[fn] = v; sum += v; sq += v * v;
            }
#pragma unroll
            for (int m = 1; m < 16; m <<= 1) { sum += __shfl_xor(sum, m); sq += __shfl_xor(sq, m); }
            const float mean = sum * (1.f / 128.f);
            const float var = sq * (1.f / 128.f) - mean * mean;
            const float rstd = rsqrtf(var + LN_EPS);
            const int row16 = rq * 4 + reg;
            const int sw = (row16 & 7) << 3;
#pragma unroll
            for (int fn = 0; fn < 8; ++fn) {
                const float o = (val[fn] - mean) * rstd * gv[fn] + bbv[fn];
                hw[row16 * 128 + ((fn * 16 + cn) ^ sw)] = f2bf(o);
            }
        }
    }

    short8 a2[4];
    {
        const int row16 = lane & 15;
        const int sw = (row16 & 7) << 3;
#pragma unroll
        for (int fk = 0; fk < 4; ++fk)
            a2[fk] = *(const short8*)(hw + row16 * 128 + ((fk * 32 + kh) ^ sw));
    }

    const short8* B2f = (const short8*)Wp2;
    f32x4 acc2[8];
#pragma unroll
    for (int fn = 0; fn < 8; ++fn) acc2[fn] = (f32x4){0.f, 0.f, 0.f, 0.f};
#pragma unroll
    for (int fk = 0; fk < 4; ++fk)
#pragma unroll
        for (int fn = 0; fn < 8; ++fn)
            acc2[fn] = __builtin_amdgcn_mfma_f32_16x16x32_bf16(a2[fk], B2f[(fn * 4 + fk) * 64 + lane], acc2[fn], 0, 0, 0);

    float bv2[8], gv[8], bbv[8];
#pragma unroll
    for (int fn = 0; fn < 8; ++fn) {
        bv2[fn] = b2[fn * 16 + cn]; gv[fn] = ln2g[fn * 16 + cn]; bbv[fn] = ln2b[fn * 16 + cn];
    }
#pragma unroll
    for (int reg = 0; reg < 4; ++reg) {
        const int gr = r0 + w * 16 + rq * 4 + reg;
        const int grc = gr < nrows ? gr : nrows - 1;
        float val[8];
        float sum = 0.f, sq = 0.f;
#pragma unroll
        for (int fn = 0; fn < 8; ++fn) {
            float v = acc2[fn][reg] + bv2[fn] + bf1f(resH[(size_t)grc * 128 + fn * 16 + cn]);
            val[fn] = v; sum += v; sq += v * v;
        }
#pragma unroll
        for (int m = 1; m < 16; m <<= 1) { sum += __shfl_xor(sum, m); sq += __shfl_xor(sq, m); }
        const float mean = sum * (1.f / 128.f);
        const float var = sq * (1.f / 128.f) - mean * mean;
        const float rstd = rsqrtf(var + LN_EPS);
        if (gr < nrows) {
#pragma unroll
            for (int fn = 0; fn < 8; ++fn)
                Cf[(size_t)gr * 128 + fn * 16 + cn] = (val[fn] - mean) * rstd * gv[fn] + bbv[fn];
        }
    }
}

// ---- histogram + per-edge rank in ONE atomic pass (8-deep ILP) ----
__global__ __launch_bounds__(256)
void hist_rank(const int* __restrict__ row, int* __restrict__ cnt,
               int* __restrict__ rank, int E)
{
    const int tid = blockIdx.x * blockDim.x + threadIdx.x;
    const int stride = gridDim.x * blockDim.x;
    for (int e0 = tid; e0 < E; e0 += stride * 8) {
        int r[8]; bool val[8];
#pragma unroll
        for (int u = 0; u < 8; ++u) {
            const int e = e0 + u * stride;
            val[u] = e < E;
            r[u] = val[u] ? row[e] : 0;
        }
        int rk[8];
#pragma unroll
        for (int u = 0; u < 8; ++u)
            if (val[u]) rk[u] = atomicAdd(&cnt[r[u]], 1);
#pragma unroll
        for (int u = 0; u < 8; ++u)
            if (val[u]) rank[e0 + u * stride] = rk[u];
    }
}

__global__ __launch_bounds__(1024)
void scan_a(const int* __restrict__ cnt, int* __restrict__ off,
            int* __restrict__ btot, int n)
{
    __shared__ int wsum[16];
    const int tid = threadIdx.x, lane = tid & 63, wv = tid >> 6;
    const int i = blockIdx.x * 1024 + tid;
    const int v = (i < n) ? cnt[i] : 0;
    int incl = v;
#pragma unroll
    for (int d = 1; d < 64; d <<= 1) { int t = __shfl_up(incl, d); if (lane >= d) incl += t; }
    if (lane == 63) wsum[wv] = incl;
    __syncthreads();
    if (tid == 0) {
        int run = 0;
        for (int ww = 0; ww < 16; ++ww) { int t = wsum[ww]; wsum[ww] = run; run += t; }
    }
    __syncthreads();
    if (i < n) off[i] = wsum[wv] + incl - v;
    if (tid == 1023) btot[blockIdx.x] = wsum[15] + incl;
}

__global__ __launch_bounds__(64)
void scan_b(int* __restrict__ btot, int* __restrict__ bexc,
            int* __restrict__ off, int n, int nb, int E)
{
    const int t = threadIdx.x;
    const int v = (t < nb) ? btot[t] : 0;
    int incl = v;
#pragma unroll
    for (int d = 1; d < 64; d <<= 1) { int u = __shfl_up(incl, d); if (t >= d) incl += u; }
    if (t < nb) bexc[t] = incl - v;
    if (t == 0) off[n] = E;
}

__global__ __launch_bounds__(1024)
void scan_c(int* __restrict__ off, const int* __restrict__ bexc, int n)
{
    const int i = blockIdx.x * 1024 + threadIdx.x;
    if (i < n) off[i] += bexc[blockIdx.x];
}

// ---- edge-parallel attention: ONE edge/quad, packed weights, META PIPELINE ----
__global__ __launch_bounds__(256, 4)
void att_edge(const unsigned short* __restrict__ xrH,
              const unsigned short* __restrict__ xcH,
              const int* __restrict__ row, const int* __restrict__ col,
              const float* __restrict__ ea, const float* __restrict__ em,
              const int* __restrict__ rank, const int* __restrict__ off,
              const unsigned* __restrict__ wpk, const float* __restrict__ b2p,
              uint2* __restrict__ catS, int E)
{
    const int lane = threadIdx.x & 63;
    const int q = lane & 3;
    const int gwid = (blockIdx.x * blockDim.x + threadIdx.x) >> 6;
    const int nw = (gridDim.x * blockDim.x) >> 6;

    unsigned wk[32];
#pragma unroll
    for (int ch = 0; ch < 4; ++ch) {
        const uint4 k0 = ((const uint4*)wpk)[ch * 8 + q * 2];
        const uint4 k1 = ((const uint4*)wpk)[ch * 8 + q * 2 + 1];
        wk[ch * 8 + 0] = k0.x; wk[ch * 8 + 1] = k0.y; wk[ch * 8 + 2] = k0.z; wk[ch * 8 + 3] = k0.w;
        wk[ch * 8 + 4] = k1.x; wk[ch * 8 + 5] = k1.y; wk[ch * 8 + 6] = k1.z; wk[ch * 8 + 7] = k1.w;
    }
    const float b2 = *b2p;

    int base = gwid * 16;
    if (base >= E) return;

    int e = base + (lane >> 2);
    bool valid = e < E;
    int ec = valid ? e : E - 1;
    int r = row[ec], c = col[ec];
    float eax = ea[ec], emv = em[ec];
    int rk = rank[ec], ofr = off[r];

    while (true) {
        const unsigned short* xr = xrH + (size_t)r * 128 + q * 8;
        const unsigned short* xc = xcH + (size_t)c * 128 + q * 8;
        uint4 pa[4], pb[4];
#pragma unroll
        for (int ch = 0; ch < 4; ++ch) {
            pa[ch] = *(const uint4*)(xr + ch * 32);
            pb[ch] = *(const uint4*)(xc + ch * 32);
        }

        const int nbase = base + nw * 16;
        const bool more = nbase < E;
        int r2 = 0, c2 = 0, rk2 = 0, ofr2 = 0;
        float eax2 = 0.f, emv2 = 0.f;
        bool valid2 = false;
        if (more) {
            const int e2 = nbase + (lane >> 2);
            valid2 = e2 < E;
            const int ec2 = valid2 ? e2 : E - 1;
            r2 = row[ec2]; c2 = col[ec2];
            eax2 = ea[ec2]; emv2 = em[ec2];
            rk2 = rank[ec2]; ofr2 = off[r2];
        }

        float pc[4];
#pragma unroll
        for (int ch = 0; ch < 4; ++ch) {
            float xa[8], xb[8];
            bf8f(pa[ch], xa); bf8f(pb[ch], xb);
            float s = 0.f;
#pragma unroll
            for (int i = 0; i < 8; ++i) {
                const unsigned wv = wk[ch * 8 + i];
                const float weF = __uint_as_float(wv << 16);
                const float w2F = __uint_as_float(wv & 0xffff0000u);
                const float t = xa[i] + xb[i] + eax * weF;
                s += t * sigf(t) * w2F;
            }
            pc[ch] = s;
        }
        float p = (pc[0] + pc[1]) + (pc[2] + pc[3]);
        p = quad_add_all(p);
        const float att = sigf(p + b2) * emv;
        if (valid && q == 0)
            catS[ofr + rk] = make_uint2((unsigned)c, __float_as_uint(att));

        if (!more) break;
        base = nbase;
        valid = valid2; r = r2; c = c2; eax = eax2; emv = emv2; rk = rk2; ofr = ofr2;
    }
}

// ---- row accumulation: msgH[r] = bf16( sum att * xm[col] ) ----
__global__ __launch_bounds__(256)
void accum_k(const unsigned short* __restrict__ xmH, const int* __restrict__ off,
             const uint2* __restrict__ catS, unsigned short* __restrict__ msgH, int N)
{
    const int lane = threadIdx.x & 63;
    const int g = lane >> 4, l = lane & 15;
    const int gwid = (blockIdx.x * blockDim.x + threadIdx.x) >> 6;
    const int nw = (gridDim.x * blockDim.x) >> 6;
    const uint4* xm4 = (const uint4*)xmH;

    for (int wid = gwid; wid < N; wid += nw) {
        int j0 = off[wid];
        const int jend = off[wid + 1];
        float acc[8] = {0.f, 0.f, 0.f, 0.f, 0.f, 0.f, 0.f, 0.f};

        for (; j0 + 16 <= jend; j0 += 16) {
            uint2 ca[4]; uint4 pk[4];
#pragma unroll
            for (int u = 0; u < 4; ++u) ca[u] = catS[j0 + u * 4 + g];
#pragma unroll
            for (int u = 0; u < 4; ++u) pk[u] = xm4[(size_t)ca[u].x * 16 + l];
#pragma unroll
            for (int u = 0; u < 4; ++u) {
                const float att = __uint_as_float(ca[u].y);
                float xm[8];
                bf8f(pk[u], xm);
#pragma unroll
                for (int i = 0; i < 8; ++i) acc[i] = fmaf(att, xm[i], acc[i]);
            }
        }
        for (; j0 + 8 <= jend; j0 += 8) {
            const uint2 caA = catS[j0 + g];
            const uint2 caB = catS[j0 + 4 + g];
            const uint4 pA = xm4[(size_t)caA.x * 16 + l];
            const uint4 pB = xm4[(size_t)caB.x * 16 + l];
            const float attA = __uint_as_float(caA.y);
            const float attB = __uint_as_float(caB.y);
            float xmA[8], xmB[8];
            bf8f(pA, xmA); bf8f(pB, xmB);
#pragma unroll
            for (int i = 0; i < 8; ++i)
                acc[i] = fmaf(attB, xmB[i], fmaf(attA, xmA[i], acc[i]));
        }
        for (; j0 < jend; j0 += 4) {
            const int je = j0 + g;
            const bool valid = je < jend;
            const int jc = valid ? je : jend - 1;
            const uint2 ca = catS[jc];
            const uint4 p = xm4[(size_t)ca.x * 16 + l];
            const float att = valid ? __uint_as_float(ca.y) : 0.f;
            float xm[8];
            bf8f(p, xm);
#pragma unroll
            for (int i = 0; i < 8; ++i) acc[i] = fmaf(att, xm[i], acc[i]);
        }

#pragma unroll
        for (int i = 0; i < 8; ++i) {
            acc[i] += __shfl_xor(acc[i], 16);
            acc[i] += __shfl_xor(acc[i], 32);
        }
        if (g == 0) {
            uint4 pk;
            pk.x = f2bf2(acc[0], acc[1]); pk.y = f2bf2(acc[2], acc[3]);
            pk.z = f2bf2(acc[4], acc[5]); pk.w = f2bf2(acc[6], acc[7]);
            ((uint4*)msgH)[(size_t)wid * 16 + l] = pk;
        }
    }
}

extern "C" void kernel_launch(void* const* d_in, const int* in_sizes, int n_in,
                              void* d_out, int out_size, void* d_ws, size_t ws_size,
                              hipStream_t stream)
{
    const float* h        = (const float*)d_in[0];
    const float* edge_attr= (const float*)d_in[1];
    const int*   row      = (const int*)d_in[2];
    const int*   col      = (const int*)d_in[3];
    const float* edge_mask= (const float*)d_in[5];
    const float* lin_w    = (const float*)d_in[6];
    const float* lin_b    = (const float*)d_in[7];
    const float* msg_w1   = (const float*)d_in[8];
    const float* msg_b1   = (const float*)d_in[9];
    const float* msg_ln_g = (const float*)d_in[10];
    const float* msg_ln_b = (const float*)d_in[11];
    const float* msg_w2   = (const float*)d_in[12];
    const float* msg_b2   = (const float*)d_in[13];
    const float* att_w1   = (const float*)d_in[14];
    const float* att_b1   = (const float*)d_in[15];
    const float* att_w2   = (const float*)d_in[16];
    const float* att_b2   = (const float*)d_in[17];
    const float* out_w1   = (const float*)d_in[18];
    const float* out_b1   = (const float*)d_in[19];
    const float* out_ln_g = (const float*)d_in[20];
    const float* out_ln_b = (const float*)d_in[21];
    const float* out_w2   = (const float*)d_in[22];
    const float* out_b2   = (const float*)d_in[23];
    const float* ln_g     = (const float*)d_in[24];
    const float* ln_b     = (const float*)d_in[25];

    const int N = in_sizes[0] / 128;
    const int E = in_sizes[2];
    const size_t NF = (size_t)N * 128;

    unsigned short* xbH  = (unsigned short*)d_ws;       // bf16 [N][128] x
    unsigned short* xrH  = xbH + NF;                    // bf16 [N][128]
    unsigned short* xcH  = xrH + NF;                    // bf16 [N][128]
    unsigned short* xmH  = xcH + NF;                    // bf16 [N][128]
    unsigned short* msgH = xmH + NF;                    // bf16 [N][128]
    int*    cnt   = (int*)(msgH + NF);                  // N
    int*    off   = cnt + N;                            // N+1 (alloc N+8)
    int*    btot  = off + N + 8;                        // 64
    int*    bexc  = btot + 64;                          // 64
    int*    rank  = bexc + 64;                          // E
    uint2*  catS  = (uint2*)(rank + E);                 // E
    unsigned short* wp = (unsigned short*)(catS + E);   // 8*16384 bf16
    float* bias256 = (float*)(wp + 8 * 16384);          // 256 f32
    unsigned* wpk  = (unsigned*)(bias256 + 256);        // 128 u32 packed (we,w2)

    const int gb = (N + 63) / 64;
    const int nb = (N + 1023) / 1024;
    const int hgrid = (E + 256 * 8 - 1) / (256 * 8);

    prep_w<<<514, 256, 0, stream>>>(lin_w, msg_w1, msg_w2, att_w1, out_w1, out_w2,
                                    att_b1, att_w2, wp, bias256, wpk);
    hipMemsetAsync(cnt, 0, (size_t)N * sizeof(int), stream);
    hist_rank<<<hgrid, 256, 0, stream>>>(row, cnt, rank, E);
    scan_a<<<nb, 1024, 0, stream>>>(cnt, off, btot, N);
    scan_b<<<1, 64, 0, stream>>>(btot, bexc, off, N, nb, E);
    scan_c<<<nb, 1024, 0, stream>>>(off, bexc, N);

    // fused front: lin -> {att_r, att_c, msg1 -> msg2}, LDS-staged B
    front_mfma<<<gb, 256, 0, stream>>>(h, wp, lin_b, att_b1,
                                       msg_b1, msg_ln_g, msg_ln_b, msg_b2,
                                       xbH, xrH, xcH, xmH, N);

    // att scalars: 1 edge/quad, packed weights, meta-pipelined, fused scatter
    att_edge<<<2048, 256, 0, stream>>>(xrH, xcH, row, col, edge_attr, edge_mask,
                                       rank, off, wpk, att_b2, catS, E);

    // msg[r] = sum att * xm[col]  (bf16 out)
    accum_k<<<2048, 256, 0, stream>>>(xmH, off, catS, msgH, N);

    // out = LN(x + (LN(silu(msg @ out_w1 + out_b1))) @ out_w2 + out_b2)
    gemm2_mfma<<<gb, 256, 0, stream>>>(msgH, wp + 5 * 16384, out_b1, out_ln_g, out_ln_b,
                                       wp + 6 * 16384, out_b2, ln_g, ln_b,
                                       xbH, (float*)d_out, N);
}